// Round 9
// baseline (1745.133 us; speedup 1.0000x reference)
//
#include <hip/hip_runtime.h>
#include <cstdint>
#include <cstddef>

// Problem constants
#define N_ 4096
#define B_ 2
#define V_ 4
#define D_ 256
#define C_ 3
#define H_ 512

#define PLANE 1048576   // N_*D_ elements per split plane
#define WPLANE 131072   // H_*D_ elements per W1T split plane
#define NEG_INF (-__builtin_inff())
#define TSTRIDE 130     // f32 tile row stride (words)

typedef __attribute__((ext_vector_type(8))) short bf16x8;   // 8 bf16 in 4 VGPRs
typedef __attribute__((ext_vector_type(4))) float f32x4;

// ---------------------------------------------------------------------------
__device__ __forceinline__ void gload16(const void* g, void* l) {
    __builtin_amdgcn_global_load_lds(
        (const __attribute__((address_space(1))) void*)g,
        (__attribute__((address_space(3))) void*)l,
        16, 0, 0);
}

// RNE float->bf16
__device__ __forceinline__ unsigned short f2bf(float x) {
    unsigned u = __builtin_bit_cast(unsigned, x);
    u += 0x7FFFu + ((u >> 16) & 1u);
    return (unsigned short)(u >> 16);
}
__device__ __forceinline__ float bf2f(unsigned short h) {
    unsigned u = ((unsigned)h) << 16;
    return __builtin_bit_cast(float, u);
}
__device__ __forceinline__ void split3(float x, unsigned short& h, unsigned short& m,
                                       unsigned short& l) {
    h = f2bf(x);
    float r = x - bf2f(h);
    m = f2bf(r);
    l = f2bf(r - bf2f(m));
}

// ---------------------------------------------------------------------------
__global__ __launch_bounds__(64) void zero_accum_kernel(float* loss_sum, int* hm) {
    int t = threadIdx.x;
    if (t < 24) loss_sum[t] = 0.0f;
    if (t < 12) hm[t] = 0;
}

// ---------------------------------------------------------------------------
// Split desc fp32 -> 3 bf16 planes per (b,v):  SP[(bv*3+l)][n][d]
__global__ __launch_bounds__(256) void split_kernel(const float* __restrict__ desc,
                                                    unsigned short* __restrict__ SP) {
    int t = blockIdx.x * 256 + threadIdx.x;
    int d4 = t & 63;
    int v  = (t >> 6) & 3;
    int n  = (t >> 8) & 4095;
    int b  = t >> 20;
    const float4 x = *(const float4*)(desc + (((size_t)(b * N_ + n) * V_ + v) << 8) + d4 * 4);
    ushort4 hv, mv, lv;
    split3(x.x, hv.x, mv.x, lv.x);
    split3(x.y, hv.y, mv.y, lv.y);
    split3(x.z, hv.z, mv.z, lv.z);
    split3(x.w, hv.w, mv.w, lv.w);
    size_t base = (size_t)((b * V_ + v) * 3) * PLANE + n * D_ + d4 * 4;
    *(ushort4*)(SP + base)              = hv;
    *(ushort4*)(SP + base + PLANE)      = mv;
    *(ushort4*)(SP + base + 2 * PLANE)  = lv;
}

// W1 [D][H] -> transposed split planes W1T[l][h][k]
__global__ __launch_bounds__(256) void w1split_kernel(const float* __restrict__ W1,
                                                      unsigned short* __restrict__ W1T) {
    int t = blockIdx.x * 256 + threadIdx.x;
    int h = t & 511;
    int k = t >> 9;
    float x = W1[(size_t)k * H_ + h];
    unsigned short hv, mv, lv;
    split3(x, hv, mv, lv);
    size_t o = (size_t)h * D_ + k;
    W1T[o] = hv; W1T[o + WPLANE] = mv; W1T[o + 2 * WPLANE] = lv;
}

// ---------------------------------------------------------------------------
__global__ __launch_bounds__(256) void norms_kernel(const float* __restrict__ desc,
                                                    float* __restrict__ invn) {
    int gw   = (blockIdx.x * 256 + threadIdx.x) >> 6;
    int lane = threadIdx.x & 63;
    int bv = gw >> 12;
    int n  = gw & (N_ - 1);
    int b  = bv >> 2, v = bv & 3;
    const float* p = desc + ((size_t)(b * N_ + n) * V_ + v) * D_;
    float4 x = *(const float4*)(p + lane * 4);
    float s = x.x * x.x + x.y * x.y + x.z * x.z + x.w * x.w;
    #pragma unroll
    for (int off = 32; off >= 1; off >>= 1) s += __shfl_xor(s, off, 64);
    if (lane == 0) invn[gw] = 1.0f / fmaxf(sqrtf(s), 1e-12f);
}

// ---------------------------------------------------------------------------
// FUSED gram + row/col softmax/argmax reductions (never materializes S).
// v4: __launch_bounds__(256,3) forces 3 blocks/CU; per-al A-fragment loads
// cut peak VGPR (~32 regs) so the forced bound doesn't spill.
// Partials: RP[(chunk*2+t)][n][8] rows, CP[strip][m][8] cols (M field = mxt).
__global__ __launch_bounds__(256, 3) void fgram_kernel(
    const unsigned short* __restrict__ SP,
    const float* __restrict__ sf,
    const float* __restrict__ invn,
    int b, int i, int j,
    float* __restrict__ RP,
    float* __restrict__ CP) {
    __shared__ __align__(16) unsigned char smraw[49152];
    __shared__ float wmax[4];
    unsigned short* stage = (unsigned short*)smraw;            // 48KB (K-loop)
    float* tile  = (float*)smraw;                              // [64][130] = 33280B
    float* CSb   = (float*)(smraw + 33280);                    // [128][9]  = 4608B
    float4* sfj4 = (float4*)(smraw + 37888);                   // [256]     = 4096B
    float4* sfi4 = (float4*)(smraw + 41984);                   // [128]     = 2048B  (ends 44032)

    const int tid = threadIdx.x;
    const int wid = tid >> 6, lane = tid & 63;
    const int wr = wid >> 1, wc = wid & 1;
    const int g = lane >> 4, ccol = lane & 15;

    const int bid = blockIdx.x;                    // 0..511 (512%8==0 -> bijective)
    const int swz = (bid & 7) * 64 + (bid >> 3);
    const int strip = swz >> 4, chunk = swz & 15;
    const int n0 = strip * 128, m0 = chunk * 256;

    const int gA = b * V_ + i, gB = b * V_ + j;

    const int q    = wid * 2;
    const int srow = lane >> 2;
    const int scol = (lane & 3) * 8;
    const int fr   = lane & 15;
    const int fk   = g * 8;

    for (int t = 0; t < 2; ++t) {
        const int brow0 = m0 + t * 128;

        f32x4 acc[4][4];
        #pragma unroll
        for (int m = 0; m < 4; ++m)
            #pragma unroll
            for (int n = 0; n < 4; ++n) acc[m][n] = (f32x4){0.f, 0.f, 0.f, 0.f};

        for (int k0 = 0; k0 < D_; k0 += 32) {
            __syncthreads();
            #pragma unroll
            for (int pl = 0; pl < 6; ++pl) {
                const unsigned short* src = (pl < 3)
                    ? (SP + (size_t)(gA * 3 + pl) * PLANE)
                    : (SP + (size_t)(gB * 3 + pl - 3) * PLANE);
                const int r0 = (pl < 3) ? n0 : brow0;
                unsigned short* ldsb = stage + pl * 4096 + q * 512;
                #pragma unroll
                for (int c = 0; c < 2; ++c) {
                    const unsigned short* gp =
                        src + ((size_t)(r0 + (q + c) * 16 + srow) << 8) + k0 + scol;
                    gload16(gp, ldsb + c * 512);
                }
            }
            __syncthreads();

            // per-al A loads (16 VGPRs) instead of af[3][4] (48 VGPRs)
            #pragma unroll
            for (int al = 0; al < 3; ++al) {
                bf16x8 af4[4];
                #pragma unroll
                for (int m = 0; m < 4; ++m)
                    af4[m] = *(const bf16x8*)(stage + al * 4096 +
                                              (wr * 64 + m * 16 + fr) * 32 + fk);
                #pragma unroll
                for (int bl = 0; bl < 3; ++bl) {
                    if (al + bl > 2) continue;
                    bf16x8 bfr[4];
                    #pragma unroll
                    for (int n = 0; n < 4; ++n)
                        bfr[n] = *(const bf16x8*)(stage + (3 + bl) * 4096 +
                                                  (wc * 64 + n * 16 + fr) * 32 + fk);
                    #pragma unroll
                    for (int m = 0; m < 4; ++m)
                        #pragma unroll
                        for (int n = 0; n < 4; ++n)
                            acc[m][n] = __builtin_amdgcn_mfma_f32_16x16x32_bf16(
                                af4[m], bfr[n], acc[m][n], 0, 0, 0);
                }
            }
        }

        // ---- tile-wide max ----
        float tmax = NEG_INF;
        #pragma unroll
        for (int m = 0; m < 4; ++m)
            #pragma unroll
            for (int n = 0; n < 4; ++n)
                #pragma unroll
                for (int r = 0; r < 4; ++r)
                    tmax = fmaxf(tmax, acc[m][n][r]);
        #pragma unroll
        for (int off = 1; off <= 32; off <<= 1)
            tmax = fmaxf(tmax, __shfl_xor(tmax, off, 64));
        if (lane == 0) wmax[wid] = tmax;
        __syncthreads();   // wmax visible; all MFMA/staging reads complete
        const float mxt = fmaxf(fmaxf(wmax[0], wmax[1]), fmaxf(wmax[2], wmax[3]));

        // load sf/invn tables into the (now free) staging-tail region
        {
            int m = m0 + t * 128 + (tid & 127);   // tile's 128 chunk cols
            if (tid < 128) {
                const float* p = sf + (((size_t)(b * N_ + m)) * V_ + j) * C_;
                sfj4[tid] = make_float4(p[0], p[1], p[2], invn[(size_t)gB * N_ + m]);
            } else {
                int n = n0 + (tid & 127);
                const float* p = sf + (((size_t)(b * N_ + n)) * V_ + i) * C_;
                sfi4[tid & 127] = make_float4(p[0], p[1], p[2], invn[(size_t)gA * N_ + n]);
            }
        }

        for (int half = 0; half < 2; ++half) {
            if (wr == half) {
                #pragma unroll
                for (int m = 0; m < 4; ++m)
                    #pragma unroll
                    for (int nf = 0; nf < 4; ++nf) {
                        int c = wc * 64 + nf * 16 + ccol;
                        int rb = m * 16 + g * 4;
                        #pragma unroll
                        for (int r = 0; r < 4; ++r)
                            tile[(rb + r) * TSTRIDE + c] = acc[m][nf][r];
                    }
            }
            __syncthreads();  // tile + sf tables visible

            // ---- row scan: 64 rows x 4 quarters, single pass ----
            {
                const int row = tid >> 2, qq = tid & 3;
                const float* rp = tile + row * TSTRIDE;
                float sum = 0.f, w0 = 0.f, w1 = 0.f, w2 = 0.f;
                float bv = NEG_INF, bif = (float)N_;
                for (int ii = 0; ii < 32; ++ii) {
                    int c = (ii << 2) + qq;
                    float s = rp[c];
                    float4 sp = sfj4[c];
                    float e = __expf(s - mxt);
                    sum += e;
                    w0 = fmaf(e, sp.x, w0); w1 = fmaf(e, sp.y, w1); w2 = fmaf(e, sp.z, w2);
                    float vv = s * sp.w;
                    float gi = (float)(m0 + t * 128 + c);
                    if (vv > bv || (vv == bv && gi < bif)) { bv = vv; bif = gi; }
                }
                #pragma unroll
                for (int off = 1; off <= 2; off <<= 1) {
                    sum += __shfl_xor(sum, off, 64);
                    w0  += __shfl_xor(w0, off, 64);
                    w1  += __shfl_xor(w1, off, 64);
                    w2  += __shfl_xor(w2, off, 64);
                    float ob = __shfl_xor(bv, off, 64);
                    float oi = __shfl_xor(bif, off, 64);
                    if (ob > bv || (ob == bv && oi < bif)) { bv = ob; bif = oi; }
                }
                if (qq == 0) {
                    float* o = RP + ((size_t)(chunk * 2 + t) * N_ + n0 + half * 64 + row) * 8;
                    *(float4*)o       = make_float4(mxt, sum, w0, w1);
                    *(float4*)(o + 4) = make_float4(w2, bv, bif, 0.f);
                }
            }

            // ---- col scan: 128 cols x 2 row-halves, single pass ----
            {
                const int c = tid >> 1, h = tid & 1;
                const float* cp = tile + (h * 32) * TSTRIDE + c;
                const int rb0 = half * 64 + h * 32;
                float sum = 0.f, w0 = 0.f, w1 = 0.f, w2 = 0.f;
                float bv = NEG_INF, bif = (float)N_;
                for (int ii = 0; ii < 32; ++ii) {
                    float s = cp[ii * TSTRIDE];
                    float4 sp = sfi4[rb0 + ii];
                    float e = __expf(s - mxt);
                    sum += e;
                    w0 = fmaf(e, sp.x, w0); w1 = fmaf(e, sp.y, w1); w2 = fmaf(e, sp.z, w2);
                    float vv = s * sp.w;
                    float gi = (float)(n0 + rb0 + ii);
                    if (vv > bv || (vv == bv && gi < bif)) { bv = vv; bif = gi; }
                }
                {
                    sum += __shfl_xor(sum, 1, 64);
                    w0  += __shfl_xor(w0, 1, 64);
                    w1  += __shfl_xor(w1, 1, 64);
                    w2  += __shfl_xor(w2, 1, 64);
                    float ob = __shfl_xor(bv, 1, 64);
                    float oi = __shfl_xor(bif, 1, 64);
                    if (ob > bv || (ob == bv && oi < bif)) { bv = ob; bif = oi; }
                }
                if (h == 0) {
                    float* cs = CSb + c * 9;
                    if (half == 0) {
                        cs[0] = sum; cs[1] = w0; cs[2] = w1; cs[3] = w2;
                        cs[4] = bv;  cs[5] = bif;
                    } else {
                        cs[0] += sum; cs[1] += w0; cs[2] += w1; cs[3] += w2;
                        if (bv > cs[4] || (bv == cs[4] && bif < cs[5])) { cs[4] = bv; cs[5] = bif; }
                    }
                }
            }
            __syncthreads();  // scans done before tile overwrite / flush
        }

        // flush col partials for this tile
        if (tid < 128) {
            const float* cs = CSb + tid * 9;
            float* o = CP + ((size_t)strip * N_ + m0 + t * 128 + tid) * 8;
            *(float4*)o       = make_float4(mxt, cs[0], cs[1], cs[2]);
            *(float4*)(o + 4) = make_float4(cs[3], cs[4], cs[5], 0.f);
        }
        // K-loop-top barrier (next t) orders flush vs restaging
    }
}

// ---------------------------------------------------------------------------
// Combine partials (K=32 both directions) -> soft + argmax indices.
// blockIdx.y = unit u (p*2+b); blockIdx.x: 0..15 rows, 16..31 cols.
__global__ __launch_bounds__(256) void comb_kernel(const float* __restrict__ PT,
                                                   float* __restrict__ soft,
                                                   int* __restrict__ idxbuf) {
    const int pi[6] = {0, 0, 0, 1, 1, 2}, pj[6] = {1, 2, 3, 2, 3, 3};
    int u = blockIdx.y, p = u >> 1, b = u & 1;
    int i = pi[p], j = pj[p];
    int x = blockIdx.x;
    int idx = (x & 15) * 256 + threadIdx.x;
    const size_t unit = (size_t)u * 64 * N_ * 8;
    const float* base;
    int dd, which;
    if (x < 16) { base = PT + unit + (size_t)idx * 8;                       dd = (i * 3 + (j - 1)) * 2 + b; which = 0; }
    else        { base = PT + unit + (size_t)32 * N_ * 8 + (size_t)idx * 8; dd = (j * 3 + i) * 2 + b;       which = 1; }

    float4 a = *(const float4*)base;
    float4 b4 = *(const float4*)(base + 4);
    float M = a.x, S = a.y, w0 = a.z, w1 = a.w, w2 = b4.x, av = b4.y, ai = b4.z;
    for (int k = 1; k < 32; ++k) {
        const float* qp = base + (size_t)k * N_ * 8;
        float4 c = *(const float4*)qp;
        float4 d = *(const float4*)(qp + 4);
        if (c.x > M) {
            float e = __expf(M - c.x);
            M = c.x;
            S  = fmaf(S,  e, c.y);
            w0 = fmaf(w0, e, c.z);
            w1 = fmaf(w1, e, c.w);
            w2 = fmaf(w2, e, d.x);
        } else {
            float e = __expf(c.x - M);
            S  = fmaf(c.y, e, S);
            w0 = fmaf(c.z, e, w0);
            w1 = fmaf(c.w, e, w1);
            w2 = fmaf(d.x, e, w2);
        }
        if (d.y > av || (d.y == av && d.z < ai)) { av = d.y; ai = d.z; }
    }
    float inv = 1.0f / S;
    float* so = soft + ((size_t)dd * N_ + idx) * 3;
    so[0] = w0 * inv; so[1] = w1 * inv; so[2] = w2 * inv;
    idxbuf[((size_t)u * 2 + which) * N_ + idx] = (int)ai;
}

// ---------------------------------------------------------------------------
__global__ __launch_bounds__(256) void mutualB_kernel(const int* __restrict__ idxbuf,
                                                      int* __restrict__ hm) {
    int u = blockIdx.y;
    int n = blockIdx.x * 256 + threadIdx.x;
    int a = idxbuf[((size_t)u * 2 + 0) * N_ + n];
    int ok = (idxbuf[((size_t)u * 2 + 1) * N_ + a] == n) ? 1 : 0;
    unsigned long long m = __ballot(ok);
    if ((threadIdx.x & 63) == 0 && m != 0ull) atomicOr(&hm[u], 1);
}

// ---------------------------------------------------------------------------
// Z GEMM (bf16x6 emulated fp32), m97-style body
template<bool BIAS>
__device__ __forceinline__ void mm6_body(
    const unsigned short* __restrict__ A0, const unsigned short* __restrict__ A1,
    const unsigned short* __restrict__ A2,
    const unsigned short* __restrict__ B0, const unsigned short* __restrict__ B1,
    const unsigned short* __restrict__ B2,
    int bx, int by,
    float* __restrict__ Cout, const float* __restrict__ bias, int ldc,
    unsigned short* smem) {
    const int tid = threadIdx.x;
    const int wid = tid >> 6, lane = tid & 63;
    const int wr = wid >> 1, wc = wid & 1;
    const int arow0 = bx * 128, brow0 = by * 128;

    f32x4 acc[4][4];
    #pragma unroll
    for (int m = 0; m < 4; ++m)
        #pragma unroll
        for (int n = 0; n < 4; ++n) acc[m][n] = (f32x4){0.f, 0.f, 0.f, 0.f};

    const unsigned short* Asrc[3] = {A0, A1, A2};
    const unsigned short* Bsrc[3] = {B0, B1, B2};
    const int q    = wid * 2;
    const int srow = lane >> 2;
    const int scol = (lane & 3) * 8;
    const int fr = lane & 15;
    const int fk = (lane >> 4) * 8;

    for (int k0 = 0; k0 < D_; k0 += 32) {
        __syncthreads();
        #pragma unroll
        for (int s = 0; s < 6; ++s) {
            const unsigned short* src = (s < 3) ? Asrc[s] : Bsrc[s - 3];
            const int r0 = (s < 3) ? arow0 : brow0;
            unsigned short* ldsb = smem + s * 4096 + q * 512;
            #pragma unroll
            for (int c = 0; c < 2; ++c) {
                const unsigned short* gp =
                    src + ((size_t)(r0 + (q + c) * 16 + srow) << 8) + k0 + scol;
                gload16(gp, ldsb + c * 512);
            }
        }
        __syncthreads();
        bf16x8 af[3][4];
        #pragma unroll
        for (int l = 0; l < 3; ++l)
            #pragma unroll
            for (int m = 0; m < 4; ++m)
                af[l][m] = *(const bf16x8*)(smem + l * 4096 +
                                            (wr * 64 + m * 16 + fr) * 32 + fk);
        #pragma unroll
        for (int bl = 0; bl < 3; ++bl) {
            bf16x8 bfr[4];
            #pragma unroll
            for (int n = 0; n < 4; ++n)
                bfr[n] = *(const bf16x8*)(smem + (3 + bl) * 4096 +
                                          (wc * 64 + n * 16 + fr) * 32 + fk);
            #pragma unroll
            for (int al = 0; al < 3; ++al) {
                if (al + bl > 2) continue;
                #pragma unroll
                for (int m = 0; m < 4; ++m)
                    #pragma unroll
                    for (int n = 0; n < 4; ++n)
                        acc[m][n] = __builtin_amdgcn_mfma_f32_16x16x32_bf16(
                            af[al][m], bfr[n], acc[m][n], 0, 0, 0);
            }
        }
    }
    const int crow = (lane >> 4) * 4;
    const int ccol = lane & 15;
    #pragma unroll
    for (int m = 0; m < 4; ++m) {
        const int gr = arow0 + wr * 64 + m * 16 + crow;
        #pragma unroll
        for (int n = 0; n < 4; ++n) {
            const int gc = brow0 + wc * 64 + n * 16 + ccol;
            f32x4 v = acc[m][n];
            float bv = BIAS ? bias[gc] : 0.0f;
            #pragma unroll
            for (int r = 0; r < 4; ++r)
                Cout[(size_t)(gr + r) * ldc + gc] = v[r] + bv;
        }
    }
}

__global__ __launch_bounds__(256) void zmm6_kernel(const unsigned short* __restrict__ SP,
                                                   const unsigned short* __restrict__ W1T,
                                                   const float* __restrict__ b1,
                                                   float* __restrict__ Z) {
    __shared__ unsigned short smem[6 * 4096];
    int bv = blockIdx.z;
    mm6_body<true>(SP + (size_t)(bv * 3 + 0) * PLANE,
                   SP + (size_t)(bv * 3 + 1) * PLANE,
                   SP + (size_t)(bv * 3 + 2) * PLANE,
                   W1T, W1T + WPLANE, W1T + 2 * WPLANE,
                   blockIdx.x, blockIdx.y,
                   Z + (size_t)bv * N_ * H_, b1, H_, smem);
}

// ---------------------------------------------------------------------------
__global__ __launch_bounds__(512) void tcode_kernel(const float* __restrict__ T,
                                                    const float* __restrict__ Wt,
                                                    float* __restrict__ tcode) {
    int dp = blockIdx.x;
    int i = dp / 3, rem = dp % 3;
    int j = rem + (rem >= i ? 1 : 0);
    int h = threadIdx.x;
    float acc = 0.0f;
    #pragma unroll
    for (int k = 0; k < 16; k++) acc = fmaf(T[i * 16 + k], Wt[k * H_ + h], acc);
    #pragma unroll
    for (int k = 0; k < 16; k++) acc = fmaf(T[j * 16 + k], Wt[(16 + k) * H_ + h], acc);
    tcode[dp * H_ + h] = acc;
}

// ---------------------------------------------------------------------------
__global__ __launch_bounds__(256) void loss_kernel(const float* __restrict__ Z,
                                                   const float* __restrict__ tcode,
                                                   const float* __restrict__ soft,
                                                   const float* __restrict__ W2,
                                                   const float* __restrict__ b2,
                                                   float* __restrict__ loss_sum) {
    int dd = blockIdx.y;
    int dp = dd >> 1, b = dd & 1;
    int i = dp / 3;
    const float* tc = tcode + (size_t)dp * H_;
    const float* zbase = Z + (size_t)((b * V_ + i) * N_) * H_;
    const float* softb = soft + (size_t)dd * N_ * C_;
    int tid = threadIdx.x;
    int wid = tid >> 6, lane = tid & 63;
    __shared__ float wsum[4];
    float sse_acc = 0.0f;
    float4 t1 = *(const float4*)(tc + lane * 4);
    float4 t2 = *(const float4*)(tc + 256 + lane * 4);
    for (int rr = wid; rr < 64; rr += 4) {
        int n = blockIdx.x * 64 + rr;
        const float* zp = zbase + (size_t)n * H_;
        float4 z1 = *(const float4*)(zp + lane * 4);
        float4 z2 = *(const float4*)(zp + 256 + lane * 4);
        float pre[8] = {z1.x + t1.x, z1.y + t1.y, z1.z + t1.z, z1.w + t1.w,
                        z2.x + t2.x, z2.y + t2.y, z2.z + t2.z, z2.w + t2.w};
        float c0 = 0.f, c1 = 0.f, c2 = 0.f;
        int h1 = lane * 4, h2 = 256 + lane * 4;
        #pragma unroll
        for (int q = 0; q < 8; q++) {
            float rv = fmaxf(pre[q], 0.0f);
            int h = (q < 4) ? (h1 + q) : (h2 + q - 4);
            c0 = fmaf(rv, W2[h * 3 + 0], c0);
            c1 = fmaf(rv, W2[h * 3 + 1], c1);
            c2 = fmaf(rv, W2[h * 3 + 2], c2);
        }
        #pragma unroll
        for (int off = 32; off >= 1; off >>= 1) {
            c0 += __shfl_xor(c0, off, 64);
            c1 += __shfl_xor(c1, off, 64);
            c2 += __shfl_xor(c2, off, 64);
        }
        if (lane == 0) {
            float e0 = c0 + b2[0] - softb[(size_t)n * C_ + 0];
            float e1 = c1 + b2[1] - softb[(size_t)n * C_ + 1];
            float e2 = c2 + b2[2] - softb[(size_t)n * C_ + 2];
            sse_acc += e0 * e0 + e1 * e1 + e2 * e2;
        }
    }
    if (lane == 0) wsum[wid] = sse_acc;
    __syncthreads();
    if (tid == 0) {
        atomicAdd(&loss_sum[dd], wsum[0] + wsum[1] + wsum[2] + wsum[3]);
    }
}

// ---------------------------------------------------------------------------
__global__ __launch_bounds__(64) void final_kernel(const float* __restrict__ loss_sum,
                                                   const int* __restrict__ hm,
                                                   float* __restrict__ out) {
    if (threadIdx.x != 0 || blockIdx.x != 0) return;
    float lt = 0.0f, cnt = 0.0f;
    for (int dp = 0; dp < 12; dp++) {
        int i = dp / 3, rem = dp % 3;
        int j = rem + (rem >= i ? 1 : 0);
        int a = i < j ? i : j, c = i < j ? j : i;
        int p = a * 3 - (a * (a - 1)) / 2 + (c - a - 1);
        for (int b = 0; b < 2; b++) {
            if (hm[p * 2 + b]) {
                lt += loss_sum[dp * 2 + b] * (1.0f / ((float)N_ * (float)C_));
                cnt += 1.0f;
            }
        }
    }
    out[0] = (cnt > 0.0f) ? (lt / cnt) : 0.0f;
}

// ---------------------------------------------------------------------------
extern "C" void kernel_launch(void* const* d_in, const int* in_sizes, int n_in,
                              void* d_out, int out_size, void* d_ws, size_t ws_size,
                              hipStream_t stream) {
    const float* desc = (const float*)d_in[0];
    const float* sf   = (const float*)d_in[1];
    const float* T    = (const float*)d_in[2];
    const float* W1   = (const float*)d_in[3];
    const float* b1   = (const float*)d_in[4];
    const float* Wt   = (const float*)d_in[5];
    const float* W2   = (const float*)d_in[6];
    const float* b2   = (const float*)d_in[7];
    float* out = (float*)d_out;

    // workspace layout
    const size_t NM = (size_t)N_ * N_;
    unsigned short* SP  = (unsigned short*)d_ws;          // 24*PLANE (50.3MB)
    unsigned short* W1T = SP + (size_t)24 * PLANE;        // 3*WPLANE
    float* w     = (float*)(W1T + (size_t)3 * WPLANE);
    float* Z     = w;                                     // NM (67MB)
    float* PT    = w + NM;                                // 12 * 64 * N_ * 8 (100.7MB)
    float* invn  = PT + (size_t)12 * 64 * N_ * 8;         // 32768
    float* tcode = invn + (size_t)B_ * V_ * N_;           // 6144
    float* soft  = tcode + 12 * H_;                       // 294912
    int*   idxbuf = (int*)(soft + (size_t)12 * B_ * N_ * C_); // 12*2*N
    float* loss_sum = (float*)(idxbuf + (size_t)12 * 2 * N_); // 24
    int*   hm    = (int*)(loss_sum + 24);                 // 12

    zero_accum_kernel<<<1, 64, 0, stream>>>(loss_sum, hm);
    split_kernel<<<8192, 256, 0, stream>>>(desc, SP);
    w1split_kernel<<<512, 256, 0, stream>>>(W1, W1T);
    norms_kernel<<<(B_ * V_ * N_) / 4, 256, 0, stream>>>(desc, invn);
    tcode_kernel<<<12, 512, 0, stream>>>(T, Wt, tcode);

    const int pairs[6][2] = {{0, 1}, {0, 2}, {0, 3}, {1, 2}, {1, 3}, {2, 3}};
    for (int p = 0; p < 6; p++) {
        int i = pairs[p][0], j = pairs[p][1];
        for (int b = 0; b < 2; b++) {
            int u = p * 2 + b;
            float* RPu = PT + (size_t)u * 64 * N_ * 8;
            float* CPu = RPu + (size_t)32 * N_ * 8;
            fgram_kernel<<<512, 256, 0, stream>>>(SP, sf, invn, b, i, j, RPu, CPu);
        }
    }

    zmm6_kernel<<<dim3(32, 4, 8), 256, 0, stream>>>(SP, W1T, b1, Z);
    comb_kernel<<<dim3(32, 12), 256, 0, stream>>>(PT, soft, idxbuf);
    mutualB_kernel<<<dim3(16, 12), 256, 0, stream>>>(idxbuf, hm);
    loss_kernel<<<dim3(64, 24), 256, 0, stream>>>(Z, tcode, soft, W2, b2, loss_sum);
    final_kernel<<<1, 64, 0, stream>>>(loss_sum, hm, out);
}

// Round 10
// 1171.776 us; speedup vs baseline: 1.4893x; 1.4893x over previous
//
#include <hip/hip_runtime.h>
#include <cstdint>
#include <cstddef>

// Problem constants
#define N_ 4096
#define B_ 2
#define V_ 4
#define D_ 256
#define C_ 3
#define H_ 512

#define PLANE 1048576   // N_*D_ elements per split plane
#define WPLANE 131072   // H_*D_ elements per W1T split plane
#define NEG_INF (-__builtin_inff())
#define TSTRIDE 130     // f32 tile row stride (words)

typedef __attribute__((ext_vector_type(8))) _Float16 f16x8;  // 8 fp16 in 4 VGPRs
typedef __attribute__((ext_vector_type(4))) float f32x4;

// ---------------------------------------------------------------------------
__device__ __forceinline__ void gload16(const void* g, void* l) {
    __builtin_amdgcn_global_load_lds(
        (const __attribute__((address_space(1))) void*)g,
        (__attribute__((address_space(3))) void*)l,
        16, 0, 0);
}

// fp16 2-way split: x = hi + lo (+ ~2^-23 |x|)
__device__ __forceinline__ void split2(float x, unsigned short& h, unsigned short& l) {
    _Float16 hh = (_Float16)x;
    float r = x - (float)hh;
    _Float16 ll = (_Float16)r;
    h = __builtin_bit_cast(unsigned short, hh);
    l = __builtin_bit_cast(unsigned short, ll);
}

// Swizzled chunk index: plane layout [R(rows/16)][Kc(8)][slot(4)][row16][e8]
// -> conflict-free ds_read_b128 of MFMA fragments (unit = g*16+fr).
__device__ __forceinline__ size_t sp_idx(int n, int d) {
    int R = n >> 4, rr = n & 15;
    int Kc = d >> 5, slot = (d >> 3) & 3, e = d & 7;
    return ((((size_t)R * 8 + Kc) * 4 + slot) * 16 + rr) * 8 + e;
}

// ---------------------------------------------------------------------------
__global__ __launch_bounds__(64) void zero_accum_kernel(float* loss_sum, int* hm) {
    int t = threadIdx.x;
    if (t < 24) loss_sum[t] = 0.0f;
    if (t < 12) hm[t] = 0;
}

// ---------------------------------------------------------------------------
// Split desc fp32 -> 2 fp16 planes per (b,v) in swizzled chunk layout.
__global__ __launch_bounds__(256) void split_kernel(const float* __restrict__ desc,
                                                    unsigned short* __restrict__ SP) {
    int t = blockIdx.x * 256 + threadIdx.x;
    int d4 = t & 63;               // 4-elem group: d = d4*4..d4*4+3
    int v  = (t >> 6) & 3;
    int n  = (t >> 8) & 4095;
    int b  = t >> 20;
    const float4 x = *(const float4*)(desc + (((size_t)(b * N_ + n) * V_ + v) << 8) + d4 * 4);
    ushort4 hv, lv;
    split2(x.x, hv.x, lv.x);
    split2(x.y, hv.y, lv.y);
    split2(x.z, hv.z, lv.z);
    split2(x.w, hv.w, lv.w);
    size_t base = (size_t)((b * V_ + v) * 2) * PLANE + sp_idx(n, d4 * 4);
    *(ushort4*)(SP + base)         = hv;
    *(ushort4*)(SP + base + PLANE) = lv;
}

// W1 [D][H] -> transposed fp16 split planes W1T[l][h][k], swizzled chunks
__global__ __launch_bounds__(256) void w1split_kernel(const float* __restrict__ W1,
                                                      unsigned short* __restrict__ W1T) {
    int t = blockIdx.x * 256 + threadIdx.x;
    int h = t & 511;
    int k = t >> 9;
    float x = W1[(size_t)k * H_ + h];
    unsigned short hv, lv;
    split2(x, hv, lv);
    size_t o = sp_idx(h, k);
    W1T[o] = hv; W1T[o + WPLANE] = lv;
}

// ---------------------------------------------------------------------------
__global__ __launch_bounds__(256) void norms_kernel(const float* __restrict__ desc,
                                                    float* __restrict__ invn) {
    int gw   = (blockIdx.x * 256 + threadIdx.x) >> 6;
    int lane = threadIdx.x & 63;
    int bv = gw >> 12;
    int n  = gw & (N_ - 1);
    int b  = bv >> 2, v = bv & 3;
    const float* p = desc + ((size_t)(b * N_ + n) * V_ + v) * D_;
    float4 x = *(const float4*)(p + lane * 4);
    float s = x.x * x.x + x.y * x.y + x.z * x.z + x.w * x.w;
    #pragma unroll
    for (int off = 32; off >= 1; off >>= 1) s += __shfl_xor(s, off, 64);
    if (lane == 0) invn[gw] = 1.0f / fmaxf(sqrtf(s), 1e-12f);
}

// ---------------------------------------------------------------------------
// FUSED gram + row/col softmax/argmax (never materializes S).  v5:
//  - fp16 2-split, 3 passes (hh, lh, hl): half the MFMA work of bf16x6
//  - swizzled chunk staging -> conflict-free fragment ds_read_b128
//  - all 12 (pair,batch) units in one dispatch (blockIdx.y = u)
// Partials: RP[(chunk*2+t)][n][8] rows, CP[strip][m][8] cols (M field = mxt).
__global__ __launch_bounds__(256) void fgram_kernel(
    const unsigned short* __restrict__ SP,
    const float* __restrict__ sf,
    const float* __restrict__ invn,
    float* __restrict__ PT) {
    __shared__ __align__(16) unsigned char smraw[49152];
    __shared__ float wmax[4];
    unsigned short* stage = (unsigned short*)smraw;            // 4 planes x 8KB = 32KB
    float* tile  = (float*)smraw;                              // [64][130] = 33280B
    float* CSb   = (float*)(smraw + 33280);                    // [128][9]  = 4608B
    float4* sfj4 = (float4*)(smraw + 37888);                   // [128]
    float4* sfi4 = (float4*)(smraw + 41984);                   // [128]

    const int tid = threadIdx.x;
    const int wid = tid >> 6, lane = tid & 63;
    const int wr = wid >> 1, wc = wid & 1;
    const int g = lane >> 4, ccol = lane & 15;

    // unit decode
    const int pi[6] = {0, 0, 0, 1, 1, 2}, pj[6] = {1, 2, 3, 2, 3, 3};
    const int u = blockIdx.y, b = u & 1;
    const int i = pi[u >> 1], j = pj[u >> 1];
    float* RP = PT + (size_t)u * 64 * N_ * 8;
    float* CP = RP + (size_t)32 * N_ * 8;

    const int bid = blockIdx.x;                    // 0..511 (512%8==0 -> bijective)
    const int swz = (bid & 7) * 64 + (bid >> 3);
    const int strip = swz >> 4, chunk = swz & 15;
    const int n0 = strip * 128, m0 = chunk * 256;

    const unsigned short* Ahi = SP + (size_t)((b * V_ + i) * 2 + 0) * PLANE;
    const unsigned short* Alo = Ahi + PLANE;
    const unsigned short* Bhi = SP + (size_t)((b * V_ + j) * 2 + 0) * PLANE;
    const unsigned short* Blo = Bhi + PLANE;
    const int gA = b * V_ + i, gB = b * V_ + j;

    const int q = wid * 2;

    for (int t = 0; t < 2; ++t) {
        const int brow0 = m0 + t * 128;
        const int RA0 = n0 >> 4, RB0 = brow0 >> 4;

        f32x4 acc[4][4];
        #pragma unroll
        for (int m = 0; m < 4; ++m)
            #pragma unroll
            for (int n = 0; n < 4; ++n) acc[m][n] = (f32x4){0.f, 0.f, 0.f, 0.f};

        for (int k0 = 0; k0 < D_; k0 += 32) {
            const int Kc = k0 >> 5;
            __syncthreads();
            const unsigned short* planes[4] = {Ahi, Alo, Bhi, Blo};
            #pragma unroll
            for (int pl = 0; pl < 4; ++pl) {
                const int R0 = (pl < 2) ? RA0 : RB0;
                #pragma unroll
                for (int c = 0; c < 2; ++c) {
                    const unsigned short* gp =
                        planes[pl] + (((size_t)(R0 + q + c) * 8 + Kc) * 512) + lane * 8;
                    gload16(gp, stage + pl * 4096 + (q + c) * 512);
                }
            }
            __syncthreads();

            // fragment base: plane + (warpRow*4+m)*512 + (g*16+fr)*8
            const int funit = (g * 16 + ccol) * 8;
            f16x8 ah[4], al4[4], bh[4];
            #pragma unroll
            for (int m = 0; m < 4; ++m) {
                ah[m]  = *(const f16x8*)(stage + 0 * 4096 + (wr * 4 + m) * 512 + funit);
                al4[m] = *(const f16x8*)(stage + 1 * 4096 + (wr * 4 + m) * 512 + funit);
                bh[m]  = *(const f16x8*)(stage + 2 * 4096 + (wc * 4 + m) * 512 + funit);
            }
            #pragma unroll
            for (int m = 0; m < 4; ++m)
                #pragma unroll
                for (int n = 0; n < 4; ++n)
                    acc[m][n] = __builtin_amdgcn_mfma_f32_16x16x32_f16(
                        ah[m], bh[n], acc[m][n], 0, 0, 0);
            #pragma unroll
            for (int m = 0; m < 4; ++m)
                #pragma unroll
                for (int n = 0; n < 4; ++n)
                    acc[m][n] = __builtin_amdgcn_mfma_f32_16x16x32_f16(
                        al4[m], bh[n], acc[m][n], 0, 0, 0);
            f16x8 bl4[4];
            #pragma unroll
            for (int n = 0; n < 4; ++n)
                bl4[n] = *(const f16x8*)(stage + 3 * 4096 + (wc * 4 + n) * 512 + funit);
            #pragma unroll
            for (int m = 0; m < 4; ++m)
                #pragma unroll
                for (int n = 0; n < 4; ++n)
                    acc[m][n] = __builtin_amdgcn_mfma_f32_16x16x32_f16(
                        ah[m], bl4[n], acc[m][n], 0, 0, 0);
        }

        // ---- tile-wide max ----
        float tmax = NEG_INF;
        #pragma unroll
        for (int m = 0; m < 4; ++m)
            #pragma unroll
            for (int n = 0; n < 4; ++n)
                #pragma unroll
                for (int r = 0; r < 4; ++r)
                    tmax = fmaxf(tmax, acc[m][n][r]);
        #pragma unroll
        for (int off = 1; off <= 32; off <<= 1)
            tmax = fmaxf(tmax, __shfl_xor(tmax, off, 64));
        if (lane == 0) wmax[wid] = tmax;
        __syncthreads();
        const float mxt = fmaxf(fmaxf(wmax[0], wmax[1]), fmaxf(wmax[2], wmax[3]));

        // load sf/invn tables into the staging-tail region
        {
            if (tid < 128) {
                int m = m0 + t * 128 + tid;
                const float* p = sf + (((size_t)(b * N_ + m)) * V_ + j) * C_;
                sfj4[tid] = make_float4(p[0], p[1], p[2], invn[(size_t)gB * N_ + m]);
            } else {
                int n = n0 + (tid & 127);
                const float* p = sf + (((size_t)(b * N_ + n)) * V_ + i) * C_;
                sfi4[tid & 127] = make_float4(p[0], p[1], p[2], invn[(size_t)gA * N_ + n]);
            }
        }

        for (int half = 0; half < 2; ++half) {
            if (wr == half) {
                #pragma unroll
                for (int m = 0; m < 4; ++m)
                    #pragma unroll
                    for (int nf = 0; nf < 4; ++nf) {
                        int c = wc * 64 + nf * 16 + ccol;
                        int rb = m * 16 + g * 4;
                        #pragma unroll
                        for (int r = 0; r < 4; ++r)
                            tile[(rb + r) * TSTRIDE + c] = acc[m][nf][r];
                    }
            }
            __syncthreads();

            // ---- row scan: 64 rows x 4 quarters, single pass ----
            {
                const int row = tid >> 2, qq = tid & 3;
                const float* rp = tile + row * TSTRIDE;
                float sum = 0.f, w0 = 0.f, w1 = 0.f, w2 = 0.f;
                float bv = NEG_INF, bif = (float)N_;
                for (int ii = 0; ii < 32; ++ii) {
                    int c = (ii << 2) + qq;
                    float s = rp[c];
                    float4 sp = sfj4[c];
                    float e = __expf(s - mxt);
                    sum += e;
                    w0 = fmaf(e, sp.x, w0); w1 = fmaf(e, sp.y, w1); w2 = fmaf(e, sp.z, w2);
                    float vv = s * sp.w;
                    float gi = (float)(m0 + t * 128 + c);
                    if (vv > bv || (vv == bv && gi < bif)) { bv = vv; bif = gi; }
                }
                #pragma unroll
                for (int off = 1; off <= 2; off <<= 1) {
                    sum += __shfl_xor(sum, off, 64);
                    w0  += __shfl_xor(w0, off, 64);
                    w1  += __shfl_xor(w1, off, 64);
                    w2  += __shfl_xor(w2, off, 64);
                    float ob = __shfl_xor(bv, off, 64);
                    float oi = __shfl_xor(bif, off, 64);
                    if (ob > bv || (ob == bv && oi < bif)) { bv = ob; bif = oi; }
                }
                if (qq == 0) {
                    float* o = RP + ((size_t)(chunk * 2 + t) * N_ + n0 + half * 64 + row) * 8;
                    *(float4*)o       = make_float4(mxt, sum, w0, w1);
                    *(float4*)(o + 4) = make_float4(w2, bv, bif, 0.f);
                }
            }

            // ---- col scan: 128 cols x 2 row-halves, single pass ----
            {
                const int c = tid >> 1, h = tid & 1;
                const float* cp = tile + (h * 32) * TSTRIDE + c;
                const int rb0 = half * 64 + h * 32;
                float sum = 0.f, w0 = 0.f, w1 = 0.f, w2 = 0.f;
                float bv = NEG_INF, bif = (float)N_;
                for (int ii = 0; ii < 32; ++ii) {
                    float s = cp[ii * TSTRIDE];
                    float4 sp = sfi4[rb0 + ii];
                    float e = __expf(s - mxt);
                    sum += e;
                    w0 = fmaf(e, sp.x, w0); w1 = fmaf(e, sp.y, w1); w2 = fmaf(e, sp.z, w2);
                    float vv = s * sp.w;
                    float gi = (float)(n0 + rb0 + ii);
                    if (vv > bv || (vv == bv && gi < bif)) { bv = vv; bif = gi; }
                }
                {
                    sum += __shfl_xor(sum, 1, 64);
                    w0  += __shfl_xor(w0, 1, 64);
                    w1  += __shfl_xor(w1, 1, 64);
                    w2  += __shfl_xor(w2, 1, 64);
                    float ob = __shfl_xor(bv, 1, 64);
                    float oi = __shfl_xor(bif, 1, 64);
                    if (ob > bv || (ob == bv && oi < bif)) { bv = ob; bif = oi; }
                }
                if (h == 0) {
                    float* cs = CSb + c * 9;
                    if (half == 0) {
                        cs[0] = sum; cs[1] = w0; cs[2] = w1; cs[3] = w2;
                        cs[4] = bv;  cs[5] = bif;
                    } else {
                        cs[0] += sum; cs[1] += w0; cs[2] += w1; cs[3] += w2;
                        if (bv > cs[4] || (bv == cs[4] && bif < cs[5])) { cs[4] = bv; cs[5] = bif; }
                    }
                }
            }
            __syncthreads();
        }

        // flush col partials for this tile
        if (tid < 128) {
            const float* cs = CSb + tid * 9;
            float* o = CP + ((size_t)strip * N_ + m0 + t * 128 + tid) * 8;
            *(float4*)o       = make_float4(mxt, cs[0], cs[1], cs[2]);
            *(float4*)(o + 4) = make_float4(cs[3], cs[4], cs[5], 0.f);
        }
    }
}

// ---------------------------------------------------------------------------
// Combine partials (K=32 both directions) -> soft + argmax indices.
__global__ __launch_bounds__(256) void comb_kernel(const float* __restrict__ PT,
                                                   float* __restrict__ soft,
                                                   int* __restrict__ idxbuf) {
    const int pi[6] = {0, 0, 0, 1, 1, 2}, pj[6] = {1, 2, 3, 2, 3, 3};
    int u = blockIdx.y, p = u >> 1, b = u & 1;
    int i = pi[p], j = pj[p];
    int x = blockIdx.x;
    int idx = (x & 15) * 256 + threadIdx.x;
    const size_t unit = (size_t)u * 64 * N_ * 8;
    const float* base;
    int dd, which;
    if (x < 16) { base = PT + unit + (size_t)idx * 8;                       dd = (i * 3 + (j - 1)) * 2 + b; which = 0; }
    else        { base = PT + unit + (size_t)32 * N_ * 8 + (size_t)idx * 8; dd = (j * 3 + i) * 2 + b;       which = 1; }

    float4 a = *(const float4*)base;
    float4 b4 = *(const float4*)(base + 4);
    float M = a.x, S = a.y, w0 = a.z, w1 = a.w, w2 = b4.x, av = b4.y, ai = b4.z;
    for (int k = 1; k < 32; ++k) {
        const float* qp = base + (size_t)k * N_ * 8;
        float4 c = *(const float4*)qp;
        float4 d = *(const float4*)(qp + 4);
        if (c.x > M) {
            float e = __expf(M - c.x);
            M = c.x;
            S  = fmaf(S,  e, c.y);
            w0 = fmaf(w0, e, c.z);
            w1 = fmaf(w1, e, c.w);
            w2 = fmaf(w2, e, d.x);
        } else {
            float e = __expf(c.x - M);
            S  = fmaf(c.y, e, S);
            w0 = fmaf(c.z, e, w0);
            w1 = fmaf(c.w, e, w1);
            w2 = fmaf(d.x, e, w2);
        }
        if (d.y > av || (d.y == av && d.z < ai)) { av = d.y; ai = d.z; }
    }
    float inv = 1.0f / S;
    float* so = soft + ((size_t)dd * N_ + idx) * 3;
    so[0] = w0 * inv; so[1] = w1 * inv; so[2] = w2 * inv;
    idxbuf[((size_t)u * 2 + which) * N_ + idx] = (int)ai;
}

// ---------------------------------------------------------------------------
__global__ __launch_bounds__(256) void mutualB_kernel(const int* __restrict__ idxbuf,
                                                      int* __restrict__ hm) {
    int u = blockIdx.y;
    int n = blockIdx.x * 256 + threadIdx.x;
    int a = idxbuf[((size_t)u * 2 + 0) * N_ + n];
    int ok = (idxbuf[((size_t)u * 2 + 1) * N_ + a] == n) ? 1 : 0;
    unsigned long long m = __ballot(ok);
    if ((threadIdx.x & 63) == 0 && m != 0ull) atomicOr(&hm[u], 1);
}

// ---------------------------------------------------------------------------
// Z GEMM: fp16 2-split, 3 passes, swizzled staging
__global__ __launch_bounds__(256) void zmm3_kernel(const unsigned short* __restrict__ SP,
                                                   const unsigned short* __restrict__ W1T,
                                                   const float* __restrict__ b1,
                                                   float* __restrict__ Z) {
    __shared__ __align__(16) unsigned short stage[4 * 4096];   // 32KB
    const int tid = threadIdx.x;
    const int wid = tid >> 6, lane = tid & 63;
    const int wr = wid >> 1, wc = wid & 1;
    const int g = lane >> 4, ccol = lane & 15;
    const int bv = blockIdx.z;
    const int arow0 = blockIdx.x * 128, bcol0 = blockIdx.y * 128;
    const int RA0 = arow0 >> 4, RB0 = bcol0 >> 4;

    const unsigned short* Ahi = SP + (size_t)(bv * 2) * PLANE;
    const unsigned short* Alo = Ahi + PLANE;
    const unsigned short* Bhi = W1T;
    const unsigned short* Blo = W1T + WPLANE;
    float* Cout = Z + (size_t)bv * N_ * H_;

    f32x4 acc[4][4];
    #pragma unroll
    for (int m = 0; m < 4; ++m)
        #pragma unroll
        for (int n = 0; n < 4; ++n) acc[m][n] = (f32x4){0.f, 0.f, 0.f, 0.f};

    const int q = wid * 2;

    for (int k0 = 0; k0 < D_; k0 += 32) {
        const int Kc = k0 >> 5;
        __syncthreads();
        const unsigned short* planes[4] = {Ahi, Alo, Bhi, Blo};
        #pragma unroll
        for (int pl = 0; pl < 4; ++pl) {
            const int R0 = (pl < 2) ? RA0 : RB0;
            #pragma unroll
            for (int c = 0; c < 2; ++c) {
                const unsigned short* gp =
                    planes[pl] + (((size_t)(R0 + q + c) * 8 + Kc) * 512) + lane * 8;
                gload16(gp, stage + pl * 4096 + (q + c) * 512);
            }
        }
        __syncthreads();

        const int funit = (g * 16 + ccol) * 8;
        f16x8 ah[4], al4[4], bh[4];
        #pragma unroll
        for (int m = 0; m < 4; ++m) {
            ah[m]  = *(const f16x8*)(stage + 0 * 4096 + (wr * 4 + m) * 512 + funit);
            al4[m] = *(const f16x8*)(stage + 1 * 4096 + (wr * 4 + m) * 512 + funit);
            bh[m]  = *(const f16x8*)(stage + 2 * 4096 + (wc * 4 + m) * 512 + funit);
        }
        #pragma unroll
        for (int m = 0; m < 4; ++m)
            #pragma unroll
            for (int n = 0; n < 4; ++n)
                acc[m][n] = __builtin_amdgcn_mfma_f32_16x16x32_f16(ah[m], bh[n], acc[m][n], 0, 0, 0);
        #pragma unroll
        for (int m = 0; m < 4; ++m)
            #pragma unroll
            for (int n = 0; n < 4; ++n)
                acc[m][n] = __builtin_amdgcn_mfma_f32_16x16x32_f16(al4[m], bh[n], acc[m][n], 0, 0, 0);
        f16x8 bl4[4];
        #pragma unroll
        for (int n = 0; n < 4; ++n)
            bl4[n] = *(const f16x8*)(stage + 3 * 4096 + (wc * 4 + n) * 512 + funit);
        #pragma unroll
        for (int m = 0; m < 4; ++m)
            #pragma unroll
            for (int n = 0; n < 4; ++n)
                acc[m][n] = __builtin_amdgcn_mfma_f32_16x16x32_f16(ah[m], bl4[n], acc[m][n], 0, 0, 0);
    }

    const int crow = (lane >> 4) * 4;
    #pragma unroll
    for (int m = 0; m < 4; ++m) {
        const int gr = arow0 + wr * 64 + m * 16 + crow;
        #pragma unroll
        for (int n = 0; n < 4; ++n) {
            const int gc = bcol0 + wc * 64 + n * 16 + ccol;
            f32x4 v = acc[m][n];
            float bvx = b1[gc];
            #pragma unroll
            for (int r = 0; r < 4; ++r)
                Cout[(size_t)(gr + r) * H_ + gc] = v[r] + bvx;
        }
    }
}

// ---------------------------------------------------------------------------
__global__ __launch_bounds__(512) void tcode_kernel(const float* __restrict__ T,
                                                    const float* __restrict__ Wt,
                                                    float* __restrict__ tcode) {
    int dp = blockIdx.x;
    int i = dp / 3, rem = dp % 3;
    int j = rem + (rem >= i ? 1 : 0);
    int h = threadIdx.x;
    float acc = 0.0f;
    #pragma unroll
    for (int k = 0; k < 16; k++) acc = fmaf(T[i * 16 + k], Wt[k * H_ + h], acc);
    #pragma unroll
    for (int k = 0; k < 16; k++) acc = fmaf(T[j * 16 + k], Wt[(16 + k) * H_ + h], acc);
    tcode[dp * H_ + h] = acc;
}

// ---------------------------------------------------------------------------
__global__ __launch_bounds__(256) void loss_kernel(const float* __restrict__ Z,
                                                   const float* __restrict__ tcode,
                                                   const float* __restrict__ soft,
                                                   const float* __restrict__ W2,
                                                   const float* __restrict__ b2,
                                                   float* __restrict__ loss_sum) {
    int dd = blockIdx.y;
    int dp = dd >> 1, b = dd & 1;
    int i = dp / 3;
    const float* tc = tcode + (size_t)dp * H_;
    const float* zbase = Z + (size_t)((b * V_ + i) * N_) * H_;
    const float* softb = soft + (size_t)dd * N_ * C_;
    int tid = threadIdx.x;
    int wid = tid >> 6, lane = tid & 63;
    __shared__ float wsum[4];
    float sse_acc = 0.0f;
    float4 t1 = *(const float4*)(tc + lane * 4);
    float4 t2 = *(const float4*)(tc + 256 + lane * 4);
    for (int rr = wid; rr < 64; rr += 4) {
        int n = blockIdx.x * 64 + rr;
        const float* zp = zbase + (size_t)n * H_;
        float4 z1 = *(const float4*)(zp + lane * 4);
        float4 z2 = *(const float4*)(zp + 256 + lane * 4);
        float pre[8] = {z1.x + t1.x, z1.y + t1.y, z1.z + t1.z, z1.w + t1.w,
                        z2.x + t2.x, z2.y + t2.y, z2.z + t2.z, z2.w + t2.w};
        float c0 = 0.f, c1 = 0.f, c2 = 0.f;
        int h1 = lane * 4, h2 = 256 + lane * 4;
        #pragma unroll
        for (int q = 0; q < 8; q++) {
            float rv = fmaxf(pre[q], 0.0f);
            int h = (q < 4) ? (h1 + q) : (h2 + q - 4);
            c0 = fmaf(rv, W2[h * 3 + 0], c0);
            c1 = fmaf(rv, W2[h * 3 + 1], c1);
            c2 = fmaf(rv, W2[h * 3 + 2], c2);
        }
        #pragma unroll
        for (int off = 32; off >= 1; off >>= 1) {
            c0 += __shfl_xor(c0, off, 64);
            c1 += __shfl_xor(c1, off, 64);
            c2 += __shfl_xor(c2, off, 64);
        }
        if (lane == 0) {
            float e0 = c0 + b2[0] - softb[(size_t)n * C_ + 0];
            float e1 = c1 + b2[1] - softb[(size_t)n * C_ + 1];
            float e2 = c2 + b2[2] - softb[(size_t)n * C_ + 2];
            sse_acc += e0 * e0 + e1 * e1 + e2 * e2;
        }
    }
    if (lane == 0) wsum[wid] = sse_acc;
    __syncthreads();
    if (tid == 0) {
        atomicAdd(&loss_sum[dd], wsum[0] + wsum[1] + wsum[2] + wsum[3]);
    }
}

// ---------------------------------------------------------------------------
__global__ __launch_bounds__(64) void final_kernel(const float* __restrict__ loss_sum,
                                                   const int* __restrict__ hm,
                                                   float* __restrict__ out) {
    if (threadIdx.x != 0 || blockIdx.x != 0) return;
    float lt = 0.0f, cnt = 0.0f;
    for (int dp = 0; dp < 12; dp++) {
        int i = dp / 3, rem = dp % 3;
        int j = rem + (rem >= i ? 1 : 0);
        int a = i < j ? i : j, c = i < j ? j : i;
        int p = a * 3 - (a * (a - 1)) / 2 + (c - a - 1);
        for (int b = 0; b < 2; b++) {
            if (hm[p * 2 + b]) {
                lt += loss_sum[dp * 2 + b] * (1.0f / ((float)N_ * (float)C_));
                cnt += 1.0f;
            }
        }
    }
    out[0] = (cnt > 0.0f) ? (lt / cnt) : 0.0f;
}

// ---------------------------------------------------------------------------
extern "C" void kernel_launch(void* const* d_in, const int* in_sizes, int n_in,
                              void* d_out, int out_size, void* d_ws, size_t ws_size,
                              hipStream_t stream) {
    const float* desc = (const float*)d_in[0];
    const float* sf   = (const float*)d_in[1];
    const float* T    = (const float*)d_in[2];
    const float* W1   = (const float*)d_in[3];
    const float* b1   = (const float*)d_in[4];
    const float* Wt   = (const float*)d_in[5];
    const float* W2   = (const float*)d_in[6];
    const float* b2   = (const float*)d_in[7];
    float* out = (float*)d_out;

    // workspace layout
    const size_t NM = (size_t)N_ * N_;
    unsigned short* SP  = (unsigned short*)d_ws;          // 16*PLANE (33.6MB)
    unsigned short* W1T = SP + (size_t)16 * PLANE;        // 2*WPLANE
    float* w     = (float*)(W1T + (size_t)2 * WPLANE);
    float* Z     = w;                                     // NM (67MB)
    float* PT    = w + NM;                                // 12 * 64 * N_ * 8 (100.7MB)
    float* invn  = PT + (size_t)12 * 64 * N_ * 8;         // 32768
    float* tcode = invn + (size_t)B_ * V_ * N_;           // 6144
    float* soft  = tcode + 12 * H_;                       // 294912
    int*   idxbuf = (int*)(soft + (size_t)12 * B_ * N_ * C_); // 12*2*N
    float* loss_sum = (float*)(idxbuf + (size_t)12 * 2 * N_); // 24
    int*   hm    = (int*)(loss_sum + 24);                 // 12

    zero_accum_kernel<<<1, 64, 0, stream>>>(loss_sum, hm);
    split_kernel<<<8192, 256, 0, stream>>>(desc, SP);
    w1split_kernel<<<512, 256, 0, stream>>>(W1, W1T);
    norms_kernel<<<(B_ * V_ * N_) / 4, 256, 0, stream>>>(desc, invn);
    tcode_kernel<<<12, 512, 0, stream>>>(T, Wt, tcode);

    fgram_kernel<<<dim3(512, 12), 256, 0, stream>>>(SP, sf, invn, PT);

    zmm3_kernel<<<dim3(32, 4, 8), 256, 0, stream>>>(SP, W1T, b1, Z);
    comb_kernel<<<dim3(32, 12), 256, 0, stream>>>(PT, soft, idxbuf);
    mutualB_kernel<<<dim3(16, 12), 256, 0, stream>>>(idxbuf, hm);
    loss_kernel<<<dim3(64, 24), 256, 0, stream>>>(Z, tcode, soft, W2, b2, loss_sum);
    final_kernel<<<1, 64, 0, stream>>>(loss_sum, hm, out);
}